// Round 3
// baseline (92.554 us; speedup 1.0000x reference)
//
#include <hip/hip_runtime.h>
#include <hip/hip_cooperative_groups.h>
#include <math.h>

namespace cg = cooperative_groups;

constexpr int B_    = 32;
constexpr int In_   = 2048;
constexpr int Din_  = 8;
constexpr int N_    = 64;
constexpr int Dout_ = 16;
constexpr int C_    = 32;
constexpr int ICP   = 64;     // In_/C_
constexpr int GRID  = 512;    // 2 blocks/CU required -> big cooperative margin
constexpr float EPS = 1e-7f;

// Single shared-memory block reused by every phase (30.25 KB).
// caps_v0's xbar[32][8] aliases the Us region.
struct Smem {
    float Us[N_][8];        // 2 KB
    float xs[ICP][8];       // 2 KB
    float lg[ICP][68];      // 17 KB (b128-aligned rows)
    float ps[4][ICP];       // 1 KB
    float inv_s[ICP];       // 256 B
    float ys[4][N_][8];     // 8 KB
};

// ---------------------------------------------------------------------------
// Phase 0: v0 = squash(sum_c W[n,c,:,:].xbar[c,:] + bias). Logical blocks
// 0..255, block = (b, j): covers n in [8j, 8j+8).
// ---------------------------------------------------------------------------
__device__ __forceinline__ void v0_body(
    Smem* sm, int blk,
    const float* __restrict__ x, const float* __restrict__ W,
    const float* __restrict__ bias, float* __restrict__ v0)
{
    const int b = blk >> 3, j = blk & 7;
    const int t = threadIdx.x;
    float (*xbar)[8] = (float(*)[8])(&sm->Us[0][0]);   // 32x8 fits in Us

    // phase 1: thread (c,k) sums its channel's 64 capsules
    {
        const int c = t >> 3, k = t & 7;
        const float* xp = x + (size_t)b * In_ * Din_ + (size_t)c * ICP * Din_ + k;
        float acc = 0.f;
        #pragma unroll 8
        for (int i = 0; i < ICP; ++i) acc += xp[i * Din_];
        xbar[c][k] = acc * (1.f / 64.f);
    }
    __syncthreads();

    // phase 2: lanes (nl = t>>5, d = (t&31)>>1, h = t&1); n = 8j+nl
    {
        const int nl = t >> 5, lane32 = t & 31;
        const int d = lane32 >> 1, h = lane32 & 1;
        const int n = j * 8 + nl;

        float a = 0.f;
        #pragma unroll
        for (int cc = 0; cc < 16; ++cc) {
            const int c2 = cc * 2 + h;
            const float4* wp = (const float4*)(W + (((size_t)n * C_ + c2) * Dout_ + d) * Din_);
            const float4 w0 = wp[0], w1 = wp[1];
            a += w0.x * xbar[c2][0] + w0.y * xbar[c2][1] + w0.z * xbar[c2][2] + w0.w * xbar[c2][3]
               + w1.x * xbar[c2][4] + w1.y * xbar[c2][5] + w1.z * xbar[c2][6] + w1.w * xbar[c2][7];
        }
        a += __shfl_xor(a, 1);              // both h-lanes: full sum over c
        a += bias[n * Dout_ + d];

        float sn = a * a;
        sn += __shfl_xor(sn, 2);
        sn += __shfl_xor(sn, 4);
        sn += __shfl_xor(sn, 8);
        sn += __shfl_xor(sn, 16);           // sum over the 16 d (same-h lanes)
        const float sc = sn / (1.f + sn) / sqrtf(sn + EPS);
        if (h == 0) v0[(size_t)b * 1024 + n * Dout_ + d] = a * sc;
    }
}

// ---------------------------------------------------------------------------
// Routing iteration body: logical block = (b, c). v_src is the ALREADY-
// ACCUMULATED routing vector (U linear in v). Writes s_out[b][c][n][d].
// ---------------------------------------------------------------------------
__device__ __forceinline__ void route_body(
    Smem* sm, int blk,
    const float* __restrict__ x, const float* __restrict__ W,
    const float* __restrict__ v_src, float* __restrict__ s_out)
{
    const int b = blk >> 5;
    const int c = blk & 31;
    const int t = threadIdx.x;
    const int w = t >> 6, l = t & 63;
    const int n4 = t >> 2, q4 = t & 3;

    // ---- U stage: thread (n4,q4) covers d in [4q4,4q4+4); quad-shfl -> k pair
    {
        const float4 vv = *(const float4*)(v_src + ((size_t)b * 64 + n4) * 16 + q4 * 4);
        const float vd[4] = {vv.x, vv.y, vv.z, vv.w};
        float pU[8] = {0, 0, 0, 0, 0, 0, 0, 0};
        #pragma unroll
        for (int dd = 0; dd < 4; ++dd) {
            const int d = q4 * 4 + dd;
            const float4* wp = (const float4*)(W + (((size_t)n4 * 32 + c) * 16 + d) * 8);
            const float4 w0 = wp[0], w1 = wp[1];
            const float v_ = vd[dd];
            pU[0] += v_ * w0.x; pU[1] += v_ * w0.y; pU[2] += v_ * w0.z; pU[3] += v_ * w0.w;
            pU[4] += v_ * w1.x; pU[5] += v_ * w1.y; pU[6] += v_ * w1.z; pU[7] += v_ * w1.w;
        }
        #pragma unroll
        for (int k = 0; k < 8; ++k) {
            pU[k] += __shfl_xor(pU[k], 1);
            pU[k] += __shfl_xor(pU[k], 2);
        }
        float2 u2; u2.x = pU[2 * q4]; u2.y = pU[2 * q4 + 1];
        *(float2*)&sm->Us[n4][2 * q4] = u2;
    }

    // ---- x fragment for lane's capsule i = l; wave 0 mirrors to LDS
    float xr[8];
    {
        const float4* xp = (const float4*)(x + ((size_t)b * In_ + c * ICP + l) * 8);
        const float4 x0 = xp[0], x1 = xp[1];
        xr[0] = x0.x; xr[1] = x0.y; xr[2] = x0.z; xr[3] = x0.w;
        xr[4] = x1.x; xr[5] = x1.y; xr[6] = x1.z; xr[7] = x1.w;
        if (w == 0) { *(float4*)&sm->xs[l][0] = x0; *(float4*)&sm->xs[l][4] = x1; }
    }
    __syncthreads();

    // ---- logits+exp: wave w covers n in [16w,16w+16); lane = i
    {
        float e[16];
        float ssum = 0.f;
        #pragma unroll
        for (int nn = 0; nn < 16; ++nn) {
            const int n = w * 16 + nn;
            const float4 u0 = *(const float4*)&sm->Us[n][0];
            const float4 u1 = *(const float4*)&sm->Us[n][4];
            const float a = u0.x * xr[0] + u0.y * xr[1] + u0.z * xr[2] + u0.w * xr[3]
                          + u1.x * xr[4] + u1.y * xr[5] + u1.z * xr[6] + u1.w * xr[7];
            const float ee = __expf(a);    // no max-pass: logits bounded (validated R3-R5)
            e[nn] = ee; ssum += ee;
        }
        #pragma unroll
        for (int qq = 0; qq < 4; ++qq) {
            float4 o;
            o.x = e[qq * 4 + 0]; o.y = e[qq * 4 + 1]; o.z = e[qq * 4 + 2]; o.w = e[qq * 4 + 3];
            *(float4*)&sm->lg[l][w * 16 + qq * 4] = o;
        }
        sm->ps[w][l] = ssum;
    }
    __syncthreads();

    if (t < 64) sm->inv_s[t] = 1.f / (sm->ps[0][t] + sm->ps[1][t] + sm->ps[2][t] + sm->ps[3][t]);
    __syncthreads();

    // ---- y stage: wave w covers i in [16w,16w+16); lane = (nq=l>>2, kq=l&3)
    {
        const int nq = l >> 2, kq = l & 3;
        float y[8] = {0, 0, 0, 0, 0, 0, 0, 0};
        #pragma unroll
        for (int ii = 0; ii < 16; ++ii) {
            const int i = w * 16 + ii;
            const float4 cw = *(const float4*)&sm->lg[i][nq * 4];
            const float iv = sm->inv_s[i];
            const float2 x2 = *(const float2*)&sm->xs[i][kq * 2];
            const float c0 = cw.x * iv, c1 = cw.y * iv, c2 = cw.z * iv, c3 = cw.w * iv;
            y[0] += c0 * x2.x; y[1] += c0 * x2.y;
            y[2] += c1 * x2.x; y[3] += c1 * x2.y;
            y[4] += c2 * x2.x; y[5] += c2 * x2.y;
            y[6] += c3 * x2.x; y[7] += c3 * x2.y;
        }
        #pragma unroll
        for (int jj = 0; jj < 4; ++jj) {
            float2 o; o.x = y[2 * jj]; o.y = y[2 * jj + 1];
            *(float2*)&sm->ys[w][nq * 4 + jj][kq * 2] = o;
        }
    }
    __syncthreads();

    // ---- s stage: thread (n4,q4): s_out[b][c][n][4q4..] = W[n,c,d,:].y[n,:]
    {
        float yn[8];
        #pragma unroll
        for (int k = 0; k < 8; ++k)
            yn[k] = sm->ys[0][n4][k] + sm->ys[1][n4][k] + sm->ys[2][n4][k] + sm->ys[3][n4][k];
        float4 o;
        float* op = (float*)&o;
        #pragma unroll
        for (int dd = 0; dd < 4; ++dd) {
            const int d = q4 * 4 + dd;
            const float4* wp = (const float4*)(W + (((size_t)n4 * 32 + c) * 16 + d) * 8);
            const float4 w0 = wp[0], w1 = wp[1];
            op[dd] = w0.x * yn[0] + w0.y * yn[1] + w0.z * yn[2] + w0.w * yn[3]
                   + w1.x * yn[4] + w1.y * yn[5] + w1.z * yn[6] + w1.w * yn[7];
        }
        *(float4*)(s_out + (((size_t)b * 32 + c) * 64 + n4) * 16 + q4 * 4) = o;
    }
}

// ---------------------------------------------------------------------------
// Reduce s over c + bias + squash -> dst; optionally dst += vadd. Logical
// blocks 0..255, block = (b, j).
// ---------------------------------------------------------------------------
__device__ __forceinline__ void reduce_body(
    int blk, const float* __restrict__ s_src, const float* __restrict__ bias,
    const float* __restrict__ vadd, float* __restrict__ dst)
{
    const int b = blk >> 3, j = blk & 7;
    const int t = threadIdx.x;
    const int nl = t >> 5, lane32 = t & 31;
    const int d = lane32 >> 1, h = lane32 & 1;
    const int n = j * 8 + nl;

    float a = 0.f;
    #pragma unroll
    for (int cc = 0; cc < 16; ++cc) {
        const int c2 = cc * 2 + h;
        a += s_src[(((size_t)b * 32 + c2) * 64 + n) * 16 + d];
    }
    a += __shfl_xor(a, 1);
    a += bias[n * Dout_ + d];

    float sn = a * a;
    sn += __shfl_xor(sn, 2);
    sn += __shfl_xor(sn, 4);
    sn += __shfl_xor(sn, 8);
    sn += __shfl_xor(sn, 16);
    const float sc = sn / (1.f + sn) / sqrtf(sn + EPS);
    float val = a * sc;
    if (vadd) val += vadd[(size_t)b * 1024 + n * Dout_ + d];
    if (h == 0) dst[(size_t)b * 1024 + n * Dout_ + d] = val;
}

// ---------------------------------------------------------------------------
// Fused cooperative kernel: 512 blocks x 256 threads -> needs only 2
// blocks/CU co-resident (LDS allows 5, launch_bounds(256,2) caps VGPR at
// 256 -> compiler guarantees >=2 waves/EU). Each block runs 2 route tiles.
// ---------------------------------------------------------------------------
__global__ __launch_bounds__(256, 2) void caps_fused(
    const float* __restrict__ x, const float* __restrict__ W,
    const float* __restrict__ bias, float* __restrict__ out,
    float* __restrict__ s1, float* __restrict__ s2,
    float* __restrict__ v0, float* __restrict__ vsum)
{
    __shared__ Smem sm;
    cg::grid_group grid = cg::this_grid();
    const int blk = blockIdx.x;

    if (blk < 256) v0_body(&sm, blk, x, W, bias, v0);
    grid.sync();

    route_body(&sm, blk, x, W, v0, s1);
    __syncthreads();
    route_body(&sm, blk + 512, x, W, v0, s1);
    grid.sync();

    if (blk < 256) reduce_body(blk, s1, bias, v0, vsum);   // vsum = v0 + v1
    grid.sync();

    route_body(&sm, blk, x, W, vsum, s2);
    __syncthreads();
    route_body(&sm, blk + 512, x, W, vsum, s2);
    grid.sync();

    if (blk < 256) reduce_body(blk, s2, bias, nullptr, out);
}

// ---------------------------------------------------------------------------
// Fallback wrappers (the proven 5-kernel R0 path)
// ---------------------------------------------------------------------------
__global__ __launch_bounds__(256) void caps_v0_k(
    const float* __restrict__ x, const float* __restrict__ W,
    const float* __restrict__ bias, float* __restrict__ v0)
{
    __shared__ Smem sm;
    v0_body(&sm, blockIdx.x, x, W, bias, v0);
}

__global__ __launch_bounds__(256) void caps_route_k(
    const float* __restrict__ x, const float* __restrict__ W,
    const float* __restrict__ v_src, float* __restrict__ s_out)
{
    __shared__ Smem sm;
    route_body(&sm, blockIdx.x, x, W, v_src, s_out);
}

__global__ __launch_bounds__(256) void caps_reduce_k(
    const float* __restrict__ s_src, const float* __restrict__ bias,
    const float* __restrict__ vadd, float* __restrict__ dst)
{
    reduce_body(blockIdx.x, s_src, bias, vadd, dst);
}

extern "C" void kernel_launch(void* const* d_in, const int* in_sizes, int n_in,
                              void* d_out, int out_size, void* d_ws, size_t ws_size,
                              hipStream_t stream) {
    const float* x    = (const float*)d_in[0];   // [B, In, Din]
    const float* W    = (const float*)d_in[1];   // [N, C, Dout, Din]
    const float* bias = (const float*)d_in[2];   // [N, Dout]
    float* out = (float*)d_out;                  // [B, N, Dout]

    float* ws   = (float*)d_ws;
    float* s1   = ws;                                   // B*C*N*Dout = 1,048,576 f
    float* s2   = s1   + (size_t)B_ * C_ * N_ * Dout_;  // 1,048,576 f
    float* v0   = s2   + (size_t)B_ * C_ * N_ * Dout_;  // B*N*Dout = 32,768 f
    float* vsum = v0   + (size_t)B_ * N_ * Dout_;       // 32,768 f

    // Decide once: cooperative path only if the runtime says the grid fits.
    static int use_coop = -1;
    if (use_coop < 0) {
        int dev = 0;
        (void)hipGetDevice(&dev);
        int occ = 0;
        (void)hipOccupancyMaxActiveBlocksPerMultiprocessor(
            &occ, (const void*)caps_fused, 256, 0);
        int cus = 0;
        (void)hipDeviceGetAttribute(&cus, hipDeviceAttributeMultiprocessorCount, dev);
        use_coop = (occ > 0 && cus > 0 && (long)occ * (long)cus >= GRID) ? 1 : 0;
    }

    if (use_coop) {
        void* args[] = {
            (void*)&x, (void*)&W, (void*)&bias, (void*)&out,
            (void*)&s1, (void*)&s2, (void*)&v0, (void*)&vsum
        };
        hipError_t e = hipLaunchCooperativeKernel((void*)caps_fused, dim3(GRID),
                                                  dim3(256), args, 0, stream);
        if (e == hipSuccess) return;
        use_coop = 0;   // fall through to the proven multi-kernel path
    }

    caps_v0_k    <<<256,  256, 0, stream>>>(x, W, bias, v0);
    caps_route_k <<<1024, 256, 0, stream>>>(x, W, v0, s1);
    caps_reduce_k<<<256,  256, 0, stream>>>(s1, bias, v0, vsum);    // vsum = v0 + v1
    caps_route_k <<<1024, 256, 0, stream>>>(x, W, vsum, s2);
    caps_reduce_k<<<256,  256, 0, stream>>>(s2, bias, nullptr, out);
}